// Round 3
// baseline (437.771 us; speedup 1.0000x reference)
//
#include <hip/hip_runtime.h>
#include <hip/hip_bf16.h>
#include <math.h>

// Sizes: B=16, N=64, nE=128, H=128, LAT=128, NS=64, NV=32, INV=96, D_NODE=160
#define SQRT3F 1.7320508075688772f
#define ALPHAF 0.10206207261596577f  // 1/sqrt(96)
#define PIF 3.14159265358979323846f

__device__ __forceinline__ float silu_f(float x) {
  return x / (1.0f + __expf(-x));
}
__device__ __forceinline__ float sigmoid_f(float x) {
  return 1.0f / (1.0f + __expf(-x));
}

// ---------------------------------------------------------------------------
// K0: per-node prep. grid=1024 (g = b*64+n), block=128.
// ---------------------------------------------------------------------------
__global__ void k_prep(const float* __restrict__ hf, const int* __restrict__ z,
                       const float* __restrict__ pos, const float* __restrict__ z_emb,
                       const float* __restrict__ vwW0, const float* __restrict__ vwb0,
                       const float* __restrict__ vwW1, const float* __restrict__ vwb1,
                       const float* __restrict__ scW0,
                       float* __restrict__ hidden, float* __restrict__ Pn,
                       float* __restrict__ Pa, float* __restrict__ xvu,
                       float* __restrict__ y1cw) {
  const int g = blockIdx.x;
  const int b = g >> 6, n = g & 63;
  const int t = threadIdx.x;

  __shared__ float vin[64];
  __shared__ float invn[96];
  __shared__ float h0[128];
  __shared__ float uS[3];
  __shared__ float rS;

  if (t == 0) {
    float px = pos[g * 3 + 0] - pos[(b * 64) * 3 + 0];
    float py = pos[g * 3 + 1] - pos[(b * 64) * 3 + 1];
    float pz = pos[g * 3 + 2] - pos[(b * 64) * 3 + 2];
    float r = sqrtf(px * px + py * py + pz * pz + 1e-12f);
    float rm = fmaxf(r, 1e-8f);
    uS[0] = px / rm; uS[1] = py / rm; uS[2] = pz / rm;
    rS = r;
  }
  __syncthreads();
  const float r = rS;

  if (t < 32) {
    int zi = z[g];
    vin[t] = z_emb[zi * 32 + t];
    const float delta = 6.0f / 31.0f;
    const float gamma = 1.0f / (delta * delta + 1e-12f);
    float rc = fminf(r, 6.0f);
    float d = rc - (float)t * delta;
    vin[32 + t] = __expf(-gamma * d * d);
  }
  if (t < 96) {
    if (t < 64) {
      invn[t] = hf[g * 160 + t];
    } else {
      int o = t - 64;
      float v0 = hf[g * 160 + 64 + o * 3 + 0];
      float v1 = hf[g * 160 + 64 + o * 3 + 1];
      float v2 = hf[g * 160 + 64 + o * 3 + 2];
      invn[t] = sqrtf((v0 * v0 + v1 * v1 + v2 * v2) * (1.0f / 3.0f) + 1e-8f);
    }
  }
  __syncthreads();

  {
    float a = vwb0[t];
    #pragma unroll 8
    for (int k = 0; k < 64; ++k) a = fmaf(vin[k], vwW0[k * 128 + t], a);
    h0[t] = silu_f(a);
  }
  __syncthreads();
  {
    float a = vwb1[t];
    #pragma unroll 8
    for (int k = 0; k < 128; ++k) a = fmaf(h0[k], vwW1[k * 128 + t], a);
    hidden[g * 128 + t] = silu_f(a);
  }
  {
    float p = 0.0f;
    #pragma unroll 8
    for (int k = 0; k < 96; ++k) p = fmaf(invn[k], scW0[(96 + k) * 128 + t], p);
    #pragma unroll 8
    for (int k = 0; k < 64; ++k) p = fmaf(vin[k], scW0[(192 + k) * 128 + t], p);
    Pn[g * 128 + t] = p;
  }
  if (n == 0) {
    float p = 0.0f;
    #pragma unroll 8
    for (int k = 0; k < 96; ++k) p = fmaf(invn[k], scW0[k * 128 + t], p);
    Pa[b * 128 + t] = p;
  }
  if (t < 32) {
    float a = hf[g * 160 + 64 + t * 3 + 0] * uS[0]
            + hf[g * 160 + 64 + t * 3 + 1] * uS[1]
            + hf[g * 160 + 64 + t * 3 + 2] * uS[2];
    xvu[g * 32 + t] = a;
  }
  if (t == 0) {
    float cw = 0.0f;
    if (r <= 6.0f && n != 0) cw = 0.5f * (cosf(PIF * r * (1.0f / 6.0f)) + 1.0f);
    y1cw[g * 4 + 0] = SQRT3F * uS[0];
    y1cw[g * 4 + 1] = SQRT3F * uS[1];
    y1cw[g * 4 + 2] = SQRT3F * uS[2];
    y1cw[g * 4 + 3] = cw;
  }
}

// ---------------------------------------------------------------------------
// KPe: Pe[e][t] = sc_b0[t] + e_feat[e]@We. grid=128, block=128.
// ---------------------------------------------------------------------------
__global__ void k_pe(const float* __restrict__ e_feat, const float* __restrict__ scW0,
                     const float* __restrict__ scb0, float* __restrict__ Pe) {
  const int e = blockIdx.x;
  const int t = threadIdx.x;
  float a = scb0[t];
  #pragma unroll
  for (int k = 0; k < 16; ++k) a = fmaf(e_feat[e * 16 + k], scW0[(256 + k) * 128 + t], a);
  Pe[e * 128 + t] = a;
}

// ---------------------------------------------------------------------------
// K2 v3: fused TP-weight GEMM + contraction.
// grid = (64 node-tiles of 16, 18 column-chunks of 512), block = 256.
// 2 cols/thread -> acc[2][16]=32 VGPRs; 8-reg prefetch double buffer now fits
// (R2 failure: acc[4][16]+wcur[16]=80 VGPRs left no room -> serialized loads).
// ---------------------------------------------------------------------------
#define TP_NT 16
__global__ void __launch_bounds__(256, 4) k_tp(
    const float* __restrict__ hidden, const float* __restrict__ W2,
    const float* __restrict__ b2, const float* __restrict__ hf,
    const float* __restrict__ xvu, const float* __restrict__ y1cw,
    float* __restrict__ values) {
  const int tile = blockIdx.x;
  const int chunk = blockIdx.y;
  const int tid = threadIdx.x;
  const int g0 = tile * TP_NT;

  __shared__ float4 hid4[TP_NT][32];
  __shared__ float xsL[TP_NT][64];
  __shared__ float xvL[TP_NT][96];
  __shared__ float xvuL[TP_NT][32];
  __shared__ float4 y1L[TP_NT];
  __shared__ float valsL[TP_NT][160];
  __shared__ float svL[TP_NT][32];

  for (int idx = tid; idx < TP_NT * 128; idx += 256) {
    int nn = idx >> 7, k = idx & 127;
    ((float*)&hid4[nn][0])[k] = hidden[(g0 + nn) * 128 + k];
  }
  for (int idx = tid; idx < TP_NT * 64; idx += 256) {
    int nn = idx >> 6, k = idx & 63;
    xsL[nn][k] = hf[(g0 + nn) * 160 + k];
  }
  for (int idx = tid; idx < TP_NT * 96; idx += 256) {
    int nn = idx / 96, k = idx - nn * 96;
    xvL[nn][k] = hf[(g0 + nn) * 160 + 64 + k];
  }
  for (int idx = tid; idx < TP_NT * 32; idx += 256) {
    int nn = idx >> 5, k = idx & 31;
    xvuL[nn][k] = xvu[(g0 + nn) * 32 + k];
    svL[nn][k] = 0.0f;
  }
  if (tid < TP_NT) y1L[tid] = ((const float4*)y1cw)[g0 + tid];
  for (int idx = tid; idx < TP_NT * 160; idx += 256) {
    valsL[idx / 160][idx % 160] = 0.0f;
  }
  __syncthreads();

  float acc[2][TP_NT];
  #pragma unroll
  for (int c = 0; c < 2; ++c)
    #pragma unroll
    for (int nn = 0; nn < TP_NT; ++nn) acc[c][nn] = 0.0f;

  const int j0 = chunk * 512 + tid;       // cols j0 and j0+256
  const float* wbase = W2 + j0;

  // wcur/wnxt layout: [c*4 + q] = W2[(kc*4+q)*9216 + j0 + c*256]
  float wcur[8], wnxt[8];
  #pragma unroll
  for (int q = 0; q < 4; ++q) {
    wcur[q]     = wbase[(size_t)q * 9216];
    wcur[4 + q] = wbase[(size_t)q * 9216 + 256];
  }

  for (int kc = 0; kc < 32; ++kc) {
    if (kc < 31) {
      const float* wp = wbase + (size_t)((kc + 1) * 4) * 9216;
      #pragma unroll
      for (int q = 0; q < 4; ++q) {
        wnxt[q]     = wp[(size_t)q * 9216];
        wnxt[4 + q] = wp[(size_t)q * 9216 + 256];
      }
    }
    #pragma unroll
    for (int nn = 0; nn < TP_NT; ++nn) {
      float4 h = hid4[nn][kc];
      acc[0][nn] = fmaf(h.x, wcur[0],
                   fmaf(h.y, wcur[1],
                   fmaf(h.z, wcur[2],
                   fmaf(h.w, wcur[3], acc[0][nn]))));
      acc[1][nn] = fmaf(h.x, wcur[4],
                   fmaf(h.y, wcur[5],
                   fmaf(h.z, wcur[6],
                   fmaf(h.w, wcur[7], acc[1][nn]))));
    }
    #pragma unroll
    for (int q = 0; q < 8; ++q) wcur[q] = wnxt[q];
  }

  // contraction: each (chunk, c) group of 256 cols lies in a single segment
  // (segment boundaries 4096/6144/7168 are all 256-aligned).
  #pragma unroll
  for (int c = 0; c < 2; ++c) {
    const int j = j0 + c * 256;
    const float bias = b2[j];
    if (j < 4096) {                       // w1: out_s[o] += xs[i]*tp
      int i = j >> 6, o = j & 63;
      #pragma unroll
      for (int nn = 0; nn < TP_NT; ++nn)
        atomicAdd(&valsL[nn][o], xsL[nn][i] * (acc[c][nn] + bias));
    } else if (j < 6144) {                // w2: sv[o] += xs[i]*tp
      int t2 = j - 4096; int i = t2 >> 5, o = t2 & 31;
      #pragma unroll
      for (int nn = 0; nn < TP_NT; ++nn)
        atomicAdd(&svL[nn][o], xsL[nn][i] * (acc[c][nn] + bias));
    } else if (j < 7168) {                // w3: out_v[o][cc] += xv[i][cc]*tp
      int t2 = j - 6144; int i = t2 >> 5, o = t2 & 31;
      #pragma unroll
      for (int nn = 0; nn < TP_NT; ++nn) {
        float tp = acc[c][nn] + bias;
        atomicAdd(&valsL[nn][64 + o * 3 + 0], xvL[nn][i * 3 + 0] * tp);
        atomicAdd(&valsL[nn][64 + o * 3 + 1], xvL[nn][i * 3 + 1] * tp);
        atomicAdd(&valsL[nn][64 + o * 3 + 2], xvL[nn][i * 3 + 2] * tp);
      }
    } else {                              // w4: out_s[o] += xvu[i]*tp
      int t2 = j - 7168; int i = t2 >> 6, o = t2 & 63;
      #pragma unroll
      for (int nn = 0; nn < TP_NT; ++nn)
        atomicAdd(&valsL[nn][o], xvuL[nn][i] * (acc[c][nn] + bias));
    }
  }
  __syncthreads();

  for (int idx = tid; idx < TP_NT * 160; idx += 256) {
    int nn = idx / 160, d = idx - nn * 160;
    float v = valsL[nn][d];
    if (d >= 64) {
      int dd = d - 64, o = dd / 3, cc = dd - o * 3;
      float4 y = y1L[nn];
      float yc = (cc == 0) ? y.x : ((cc == 1) ? y.y : y.z);
      v = fmaf(svL[nn][o], yc, v);
    }
    atomicAdd(&values[(g0 + nn) * 160 + d], ALPHAF * v);
  }
}

// ---------------------------------------------------------------------------
// K3: gate MLP + aggregation per (b,e). grid=2048, block=256.
// Full A staged in LDS once; barrier-free main K-loop streaming W1 from L2.
// ---------------------------------------------------------------------------
__global__ void __launch_bounds__(256) k_gate_agg(
    const float* __restrict__ Pa, const float* __restrict__ Pe,
    const float* __restrict__ Pn, const float* __restrict__ W1,
    const float* __restrict__ b1, const float* __restrict__ W2v,
    const float* __restrict__ b2s, const float* __restrict__ y1cw,
    const float* __restrict__ values, float* __restrict__ inv_agg) {
  const int bid = blockIdx.x;
  const int b = bid >> 7, e = bid & 127;
  const int tid = threadIdx.x;

  __shared__ float A[64][129];
  __shared__ float Prow[128];
  __shared__ float gpart[64][17];
  __shared__ float gateL[64];
  __shared__ float aggL[160];
  __shared__ float normS;

  if (tid < 128) Prow[tid] = Pa[b * 128 + tid] + Pe[e * 128 + tid];
  __syncthreads();
  {
    const float* pn = Pn + (size_t)b * 64 * 128;
    for (int idx = tid; idx < 8192; idx += 256) {
      int n = idx >> 7, k = idx & 127;
      A[n][k] = silu_f(pn[idx] + Prow[k]);
    }
  }
  __syncthreads();

  const int rowg = tid >> 4, colg = tid & 15;
  const int r4 = rowg * 4, c8 = colg * 8;

  float acc[4][8];
  #pragma unroll
  for (int i = 0; i < 4; ++i)
    #pragma unroll
    for (int jj = 0; jj < 8; ++jj) acc[i][jj] = 0.0f;

  const float* wptr = W1 + c8;
  #pragma unroll 4
  for (int k = 0; k < 128; ++k) {
    float4 w0 = *(const float4*)(wptr + k * 128);
    float4 w1v = *(const float4*)(wptr + k * 128 + 4);
    float av0 = A[r4 + 0][k];
    float av1 = A[r4 + 1][k];
    float av2 = A[r4 + 2][k];
    float av3 = A[r4 + 3][k];
    float wv[8] = {w0.x, w0.y, w0.z, w0.w, w1v.x, w1v.y, w1v.z, w1v.w};
    #pragma unroll
    for (int jj = 0; jj < 8; ++jj) {
      acc[0][jj] = fmaf(av0, wv[jj], acc[0][jj]);
      acc[1][jj] = fmaf(av1, wv[jj], acc[1][jj]);
      acc[2][jj] = fmaf(av2, wv[jj], acc[2][jj]);
      acc[3][jj] = fmaf(av3, wv[jj], acc[3][jj]);
    }
  }

  float p[4] = {0.0f, 0.0f, 0.0f, 0.0f};
  #pragma unroll
  for (int jj = 0; jj < 8; ++jj) {
    float bb = b1[c8 + jj];
    float wg = W2v[c8 + jj];
    #pragma unroll
    for (int i = 0; i < 4; ++i) {
      float h = silu_f(acc[i][jj] + bb);
      p[i] = fmaf(h, wg, p[i]);
    }
  }
  #pragma unroll
  for (int i = 0; i < 4; ++i) gpart[r4 + i][colg] = p[i];
  __syncthreads();

  if (tid < 64) {
    float s = 0.0f;
    #pragma unroll
    for (int cg = 0; cg < 16; ++cg) s += gpart[tid][cg];
    float gv = sigmoid_f(s + b2s[0]);
    gv *= y1cw[(b * 64 + tid) * 4 + 3];
    gateL[tid] = gv;
    float t = gv;
    #pragma unroll
    for (int off = 32; off > 0; off >>= 1) t += __shfl_down(t, off);
    if (tid == 0) normS = fmaxf(t, 1e-8f);
  }
  __syncthreads();

  if (tid < 160) {
    float a = 0.0f;
    const float* vp = values + (size_t)b * 64 * 160 + tid;
    #pragma unroll 4
    for (int n = 0; n < 64; ++n) a = fmaf(gateL[n], vp[n * 160], a);
    aggL[tid] = a / normS;
  }
  __syncthreads();
  if (tid < 96) {
    float rv;
    if (tid < 64) {
      rv = aggL[tid];
    } else {
      int o = tid - 64;
      float a0 = aggL[64 + o * 3 + 0];
      float a1 = aggL[64 + o * 3 + 1];
      float a2 = aggL[64 + o * 3 + 2];
      rv = sqrtf((a0 * a0 + a1 * a1 + a2 * a2) * (1.0f / 3.0f) + 1e-8f);
    }
    inv_agg[bid * 96 + tid] = rv;
  }
}

// ---------------------------------------------------------------------------
// K4: MLP layer Y = act(X@W + b). 32-row tiles -> 64 blocks. K in {96,128}.
// ---------------------------------------------------------------------------
__global__ void __launch_bounds__(256) k_mlp(
    const float* __restrict__ X, const float* __restrict__ W,
    const float* __restrict__ bias, float* __restrict__ Y,
    int K, int act) {
  const int r0 = blockIdx.x * 32;
  const int tid = threadIdx.x;

  __shared__ float A[32][129];

  for (int idx = tid; idx < 32 * K; idx += 256) {
    int n = idx / K, k = idx - n * K;
    A[n][k] = X[(size_t)(r0 + n) * K + k];
  }
  __syncthreads();

  const int rowg = tid >> 4, colg = tid & 15;
  const int r2 = rowg * 2, c8 = colg * 8;

  float acc[2][8];
  #pragma unroll
  for (int i = 0; i < 2; ++i)
    #pragma unroll
    for (int jj = 0; jj < 8; ++jj) acc[i][jj] = 0.0f;

  const float* wptr = W + c8;
  #pragma unroll 4
  for (int k = 0; k < K; ++k) {
    float4 w0 = *(const float4*)(wptr + k * 128);
    float4 w1v = *(const float4*)(wptr + k * 128 + 4);
    float av0 = A[r2 + 0][k];
    float av1 = A[r2 + 1][k];
    float wv[8] = {w0.x, w0.y, w0.z, w0.w, w1v.x, w1v.y, w1v.z, w1v.w};
    #pragma unroll
    for (int jj = 0; jj < 8; ++jj) {
      acc[0][jj] = fmaf(av0, wv[jj], acc[0][jj]);
      acc[1][jj] = fmaf(av1, wv[jj], acc[1][jj]);
    }
  }

  #pragma unroll
  for (int jj = 0; jj < 8; ++jj) {
    float bb = bias[c8 + jj];
    #pragma unroll
    for (int i = 0; i < 2; ++i) {
      float v = acc[i][jj] + bb;
      if (act) v = silu_f(v);
      Y[(size_t)(r0 + r2 + i) * 128 + c8 + jj] = v;
    }
  }
}

// ---------------------------------------------------------------------------
extern "C" void kernel_launch(void* const* d_in, const int* in_sizes, int n_in,
                              void* d_out, int out_size, void* d_ws, size_t ws_size,
                              hipStream_t stream) {
  const float* hf    = (const float*)d_in[0];
  const int*   z     = (const int*)  d_in[1];
  const float* pos   = (const float*)d_in[2];
  const float* e_feat= (const float*)d_in[4];
  const float* z_emb = (const float*)d_in[5];
  const float* vwW0  = (const float*)d_in[6];
  const float* vwb0  = (const float*)d_in[7];
  const float* vwW1  = (const float*)d_in[8];
  const float* vwb1  = (const float*)d_in[9];
  const float* vwW2  = (const float*)d_in[10];
  const float* vwb2  = (const float*)d_in[11];
  const float* scW0  = (const float*)d_in[12];
  const float* scb0  = (const float*)d_in[13];
  const float* scW1  = (const float*)d_in[14];
  const float* scb1  = (const float*)d_in[15];
  const float* scW2  = (const float*)d_in[16];
  const float* scb2  = (const float*)d_in[17];
  const float* oW0   = (const float*)d_in[18];
  const float* ob0   = (const float*)d_in[19];
  const float* oW1   = (const float*)d_in[20];
  const float* ob1   = (const float*)d_in[21];
  const float* oW2   = (const float*)d_in[22];
  const float* ob2   = (const float*)d_in[23];
  float* out = (float*)d_out;

  float* ws = (float*)d_ws;
  float* hidden = ws;                 // 1024*128
  float* Pn     = hidden + 131072;    // 1024*128
  float* Pa     = Pn + 131072;        // 16*128
  float* Pe     = Pa + 2048;          // 128*128
  float* xvu    = Pe + 16384;         // 1024*32
  float* y1cw   = xvu + 32768;        // 1024*4
  float* values = y1cw + 4096;        // 1024*160
  float* invagg = values + 163840;    // 2048*96
  float* H1     = invagg + 196608;    // 2048*128
  float* H2     = H1 + 262144;        // 2048*128

  hipMemsetAsync(values, 0, 163840 * sizeof(float), stream);

  k_prep<<<1024, 128, 0, stream>>>(hf, z, pos, z_emb, vwW0, vwb0, vwW1, vwb1,
                                   scW0, hidden, Pn, Pa, xvu, y1cw);
  k_pe<<<128, 128, 0, stream>>>(e_feat, scW0, scb0, Pe);
  k_tp<<<dim3(64, 18), 256, 0, stream>>>(hidden, vwW2, vwb2, hf, xvu, y1cw, values);
  k_gate_agg<<<2048, 256, 0, stream>>>(Pa, Pe, Pn, scW1, scb1, scW2, scb2,
                                       y1cw, values, invagg);
  k_mlp<<<64, 256, 0, stream>>>(invagg, oW0, ob0, H1, 96, 1);
  k_mlp<<<64, 256, 0, stream>>>(H1, oW1, ob1, H2, 128, 1);
  k_mlp<<<64, 256, 0, stream>>>(H2, oW2, ob2, out, 128, 0);
}